// Round 3
// baseline (400.282 us; speedup 1.0000x reference)
//
#include <hip/hip_runtime.h>

#define Bsz  4
#define Tseq 2048
#define Cdim 512
#define Hn   8
#define Dh   64
#define BT   8192     // Bsz*Tseq tokens
#define NQKV 1536
#define NEG_BIG (-1e30f)

typedef __attribute__((ext_vector_type(8))) short bf16x8;  // 8 bf16 = 4 VGPRs
typedef __attribute__((ext_vector_type(4))) float f32x4;

__device__ __forceinline__ float b2f(short s) {
    unsigned u = ((unsigned)(unsigned short)s) << 16;
    float f; __builtin_memcpy(&f, &u, 4); return f;
}
__device__ __forceinline__ short f2b(float f) {
    unsigned u; __builtin_memcpy(&u, &f, 4);
    u = (u + 0x7fffu + ((u >> 16) & 1u)) >> 16;   // RNE
    return (short)u;
}

// ---------------- weight transpose + bf16 cast: W[c][n] (fp32) -> Wt[n][c] (bf16) ----------------
__global__ __launch_bounds__(256) void k_transpose(const float* __restrict__ wq, const float* __restrict__ wk,
                                                   const float* __restrict__ wv, const float* __restrict__ wff,
                                                   short* __restrict__ wqkvt, short* __restrict__ wfft) {
    int idx = blockIdx.x * 256 + threadIdx.x;     // grid covers 1536*512 + 512*512 = 1048576 exactly
    if (idx < NQKV * Cdim) {
        int n = idx >> 9, c = idx & 511;
        int proj = n >> 9, nn = n & 511;
        int h = nn >> 6, d = nn & 63;
        const float* w = (proj == 0) ? wq : (proj == 1 ? wk : wv);
        wqkvt[idx] = f2b(w[(h * Cdim + c) * Dh + d]);
    } else {
        int i2 = idx - NQKV * Cdim;
        int n = i2 >> 9, c = i2 & 511;
        wfft[i2] = f2b(wff[c * Cdim + n]);
    }
}

// ---------------- LayerNorm: fp32 in, bf16 out ----------------
__global__ __launch_bounds__(256) void k_ln(const float* __restrict__ x, const float* __restrict__ g,
                                            const float* __restrict__ b, short* __restrict__ out) {
    int row  = blockIdx.x * 4 + (threadIdx.x >> 6);   // one wave per token row
    int lane = threadIdx.x & 63;
    const f32x4 a0 = *(const f32x4*)(x + row * Cdim + lane * 8);
    const f32x4 a1 = *(const f32x4*)(x + row * Cdim + lane * 8 + 4);
    float v[8] = {a0[0], a0[1], a0[2], a0[3], a1[0], a1[1], a1[2], a1[3]};
    float s = 0.f, sq = 0.f;
#pragma unroll
    for (int i = 0; i < 8; i++) { s += v[i]; sq += v[i] * v[i]; }
#pragma unroll
    for (int off = 1; off < 64; off <<= 1) { s += __shfl_xor(s, off); sq += __shfl_xor(sq, off); }
    float mean = s * (1.f / 512.f);
    float var  = sq * (1.f / 512.f) - mean * mean;
    float rstd = rsqrtf(var + 1e-5f);
    const f32x4 g0 = *(const f32x4*)(g + lane * 8);
    const f32x4 g1 = *(const f32x4*)(g + lane * 8 + 4);
    const f32x4 b0 = *(const f32x4*)(b + lane * 8);
    const f32x4 b1 = *(const f32x4*)(b + lane * 8 + 4);
    float gg[8] = {g0[0], g0[1], g0[2], g0[3], g1[0], g1[1], g1[2], g1[3]};
    float bb[8] = {b0[0], b0[1], b0[2], b0[3], b1[0], b1[1], b1[2], b1[3]};
    bf16x8 o;
#pragma unroll
    for (int i = 0; i < 8; i++) o[i] = f2b((v[i] - mean) * rstd * gg[i] + bb[i]);
    *(bf16x8*)(out + row * Cdim + lane * 8) = o;
}

// ---------------- QKV GEMM: [8192,512] x Wt[1536,512], all bf16 ----------------
// wave computes 64 rows x 64 cols (4x4 tiles of 16x16x32 MFMA), frags direct from global.
__global__ __launch_bounds__(256) void k_gemm_qkv(const short* __restrict__ A, const short* __restrict__ Wt,
                                                  short* __restrict__ q, short* __restrict__ k,
                                                  short* __restrict__ vt) {
    const int wave = threadIdx.x >> 6, lane = threadIdx.x & 63;
    const int quad = lane >> 4, l15 = lane & 15;
    const int m0 = blockIdx.x * 256 + wave * 64;
    const int n0 = blockIdx.y * 64;
    f32x4 acc[4][4];
#pragma unroll
    for (int i = 0; i < 4; i++)
#pragma unroll
        for (int j = 0; j < 4; j++) acc[i][j] = (f32x4){0.f, 0.f, 0.f, 0.f};
    const short* Ab = A  + (m0 + l15) * Cdim + quad * 8;
    const short* Bb = Wt + (n0 + l15) * Cdim + quad * 8;
#pragma unroll 2
    for (int ks = 0; ks < 16; ks++) {
        bf16x8 a[4], w[4];
#pragma unroll
        for (int mt = 0; mt < 4; mt++) a[mt] = *(const bf16x8*)(Ab + mt * 16 * Cdim + ks * 32);
#pragma unroll
        for (int nt = 0; nt < 4; nt++) w[nt] = *(const bf16x8*)(Bb + nt * 16 * Cdim + ks * 32);
#pragma unroll
        for (int mt = 0; mt < 4; mt++)
#pragma unroll
            for (int nt = 0; nt < 4; nt++)
                acc[mt][nt] = __builtin_amdgcn_mfma_f32_16x16x32_bf16(a[mt], w[nt], acc[mt][nt], 0, 0, 0);
    }
    // epilogue: whole block lies in one projection + one head (n-tile = 64 = head size)
    const int proj = n0 >> 9;
    const int hh   = (n0 & 511) >> 6;
#pragma unroll
    for (int mt = 0; mt < 4; mt++) {
#pragma unroll
        for (int r = 0; r < 4; r++) {
            int t  = m0 + mt * 16 + quad * 4 + r;
            int bi = t >> 11, tt = t & 2047;
#pragma unroll
            for (int nt = 0; nt < 4; nt++) {
                int d = nt * 16 + l15;
                short val = f2b(acc[mt][nt][r]);
                if (proj == 0)      q [((bi * Hn + hh) * Tseq + tt) * Dh + d] = val;
                else if (proj == 1) k [((bi * Hn + hh) * Tseq + tt) * Dh + d] = val;
                else                vt[((bi * Hn + hh) * Dh + d) * Tseq + tt] = val;
            }
        }
    }
}

// ---------------- causal flash attention ----------------
// block = 4 waves; wave owns 16 q rows. Block-UNIFORM key-tile count (2*qt+2) so
// __syncthreads() can guard the P LDS transpose; fully-masked extra tiles are benign
// under the -1e30 sentinel (rmax=-1e30 -> alpha=1, p=0).
__global__ __launch_bounds__(256) void k_attn(const short* __restrict__ qb, const short* __restrict__ kb,
                                              const short* __restrict__ vtb, const float* __restrict__ x,
                                              float* __restrict__ out1) {
    const int wave = threadIdx.x >> 6, lane = threadIdx.x & 63;
    const int quad = lane >> 4, l15 = lane & 15;
    const int qt = blockIdx.x, bh = blockIdx.y;
    const int q0 = qt * 64 + wave * 16;
    const short* Q = qb  + bh * Tseq * Dh;
    const short* K = kb  + bh * Tseq * Dh;
    const short* V = vtb + bh * Dh * Tseq;      // [d][s]

    __shared__ __align__(16) short psh[4][16 * 40];  // per-wave 16x32 P tile, stride 40
    short* pw = psh[wave];

    bf16x8 qa[2];
#pragma unroll
    for (int ks = 0; ks < 2; ks++)
        qa[ks] = *(const bf16x8*)(Q + (q0 + l15) * Dh + ks * 32 + quad * 8);

    f32x4 o[4];
#pragma unroll
    for (int i = 0; i < 4; i++) o[i] = (f32x4){0.f, 0.f, 0.f, 0.f};
    float m_i[4], l_i[4];
#pragma unroll
    for (int r = 0; r < 4; r++) { m_i[r] = NEG_BIG; l_i[r] = 0.f; }

    const float sc = 0.125f * 1.44269504089f;   // scale * log2(e): softmax in exp2 domain
    const int nkt = 2 * qt + 2;                 // block-uniform: covers keys <= qt*64+63
    for (int kt = 0; kt < nkt; kt++) {
        const int s0 = kt * 32;
        f32x4 s[2];
#pragma unroll
        for (int nt = 0; nt < 2; nt++) {
            bf16x8 k0 = *(const bf16x8*)(K + (s0 + nt * 16 + l15) * Dh + quad * 8);
            bf16x8 k1 = *(const bf16x8*)(K + (s0 + nt * 16 + l15) * Dh + 32 + quad * 8);
            f32x4 z = (f32x4){0.f, 0.f, 0.f, 0.f};
            z = __builtin_amdgcn_mfma_f32_16x16x32_bf16(qa[0], k0, z, 0, 0, 0);
            z = __builtin_amdgcn_mfma_f32_16x16x32_bf16(qa[1], k1, z, 0, 0, 0);
            s[nt] = z;
        }
        float rmax[4];
#pragma unroll
        for (int r = 0; r < 4; r++) rmax[r] = NEG_BIG;
#pragma unroll
        for (int nt = 0; nt < 2; nt++)
#pragma unroll
            for (int r = 0; r < 4; r++) {
                int row = q0 + quad * 4 + r;
                int col = s0 + nt * 16 + l15;
                float v = s[nt][r] * sc;
                if (col > row) v = NEG_BIG;
                s[nt][r] = v;
                rmax[r] = fmaxf(rmax[r], v);
            }
#pragma unroll
        for (int r = 0; r < 4; r++)
#pragma unroll
            for (int off = 1; off < 16; off <<= 1)
                rmax[r] = fmaxf(rmax[r], __shfl_xor(rmax[r], off));
        float alpha[4], rsum[4];
#pragma unroll
        for (int r = 0; r < 4; r++) {
            float mn = fmaxf(m_i[r], rmax[r]);
            alpha[r] = __builtin_amdgcn_exp2f(m_i[r] - mn);   // finite-finite: never NaN
            m_i[r] = mn;
            rsum[r] = 0.f;
        }
#pragma unroll
        for (int nt = 0; nt < 2; nt++)
#pragma unroll
            for (int r = 0; r < 4; r++) {
                float p = __builtin_amdgcn_exp2f(s[nt][r] - m_i[r]);  // masked -> exp2(-1e30)=0
                s[nt][r] = p;
                rsum[r] += p;
            }
#pragma unroll
        for (int r = 0; r < 4; r++)
#pragma unroll
            for (int off = 1; off < 16; off <<= 1)
                rsum[r] += __shfl_xor(rsum[r], off);
#pragma unroll
        for (int r = 0; r < 4; r++) l_i[r] = l_i[r] * alpha[r] + rsum[r];
#pragma unroll
        for (int v4 = 0; v4 < 4; v4++)
#pragma unroll
            for (int r = 0; r < 4; r++) o[v4][r] *= alpha[r];
        // P: C-layout -> LDS -> A-layout, barrier-guarded (uniform trip count)
        __syncthreads();
#pragma unroll
        for (int nt = 0; nt < 2; nt++)
#pragma unroll
            for (int r = 0; r < 4; r++)
                pw[(quad * 4 + r) * 40 + nt * 16 + l15] = f2b(s[nt][r]);
        __syncthreads();
        bf16x8 pa = *(const bf16x8*)(pw + l15 * 40 + quad * 8);
#pragma unroll
        for (int v4 = 0; v4 < 4; v4++) {
            bf16x8 vb = *(const bf16x8*)(V + (v4 * 16 + l15) * Tseq + s0 + quad * 8);
            o[v4] = __builtin_amdgcn_mfma_f32_16x16x32_bf16(pa, vb, o[v4], 0, 0, 0);
        }
    }
    // epilogue: out1 = x + O/l  (fp32); l_i >= 1 always (tile 0 has an unmasked col per row)
    const int bi = bh >> 3, hh = bh & 7;
#pragma unroll
    for (int v4 = 0; v4 < 4; v4++)
#pragma unroll
        for (int r = 0; r < 4; r++) {
            int t   = q0 + quad * 4 + r;
            int idx = (bi * Tseq + t) * Cdim + hh * Dh + v4 * 16 + l15;
            out1[idx] = x[idx] + o[v4][r] / l_i[r];
        }
}

// ---------------- FF GEMM: [8192,512] x Wt[512,512], fused bias+ReLU+residual, fp32 out ----------------
__global__ __launch_bounds__(256) void k_gemm_ff(const short* __restrict__ A, const short* __restrict__ Wt,
                                                 const float* __restrict__ bias, const float* __restrict__ res,
                                                 float* __restrict__ out) {
    const int wave = threadIdx.x >> 6, lane = threadIdx.x & 63;
    const int quad = lane >> 4, l15 = lane & 15;
    const int m0 = blockIdx.x * 256 + wave * 64;
    const int n0 = blockIdx.y * 64;
    f32x4 acc[4][4];
#pragma unroll
    for (int i = 0; i < 4; i++)
#pragma unroll
        for (int j = 0; j < 4; j++) acc[i][j] = (f32x4){0.f, 0.f, 0.f, 0.f};
    const short* Ab = A  + (m0 + l15) * Cdim + quad * 8;
    const short* Bb = Wt + (n0 + l15) * Cdim + quad * 8;
#pragma unroll 2
    for (int ks = 0; ks < 16; ks++) {
        bf16x8 a[4], w[4];
#pragma unroll
        for (int mt = 0; mt < 4; mt++) a[mt] = *(const bf16x8*)(Ab + mt * 16 * Cdim + ks * 32);
#pragma unroll
        for (int nt = 0; nt < 4; nt++) w[nt] = *(const bf16x8*)(Bb + nt * 16 * Cdim + ks * 32);
#pragma unroll
        for (int mt = 0; mt < 4; mt++)
#pragma unroll
            for (int nt = 0; nt < 4; nt++)
                acc[mt][nt] = __builtin_amdgcn_mfma_f32_16x16x32_bf16(a[mt], w[nt], acc[mt][nt], 0, 0, 0);
    }
#pragma unroll
    for (int mt = 0; mt < 4; mt++) {
#pragma unroll
        for (int r = 0; r < 4; r++) {
            int t = m0 + mt * 16 + quad * 4 + r;
#pragma unroll
            for (int nt = 0; nt < 4; nt++) {
                int n = n0 + nt * 16 + l15;
                float fv = acc[mt][nt][r] + bias[n];
                fv = fmaxf(fv, 0.f);
                out[t * Cdim + n] = res[t * Cdim + n] + fv;
            }
        }
    }
}

extern "C" void kernel_launch(void* const* d_in, const int* in_sizes, int n_in,
                              void* d_out, int out_size, void* d_ws, size_t ws_size,
                              hipStream_t stream) {
    const float* x   = (const float*)d_in[0];
    const float* wq  = (const float*)d_in[1];
    const float* wk  = (const float*)d_in[2];
    const float* wv  = (const float*)d_in[3];
    const float* wff = (const float*)d_in[4];
    const float* bff = (const float*)d_in[5];
    const float* g1  = (const float*)d_in[6];
    const float* b1  = (const float*)d_in[7];
    const float* g2  = (const float*)d_in[8];
    const float* b2  = (const float*)d_in[9];

    char* p = (char*)d_ws;                                  // ~50 MB total scratch
    short* wqkvt = (short*)p; p += (size_t)NQKV * Cdim * 2;
    short* wfft  = (short*)p; p += (size_t)Cdim * Cdim * 2;
    short* h1    = (short*)p; p += (size_t)BT * Cdim * 2;   // reused as h2 after attention
    short* qb    = (short*)p; p += (size_t)BT * Cdim * 2;
    short* kb    = (short*)p; p += (size_t)BT * Cdim * 2;
    short* vtb   = (short*)p; p += (size_t)BT * Cdim * 2;
    float* out1  = (float*)p; p += (size_t)BT * Cdim * 4;

    hipLaunchKernelGGL(k_transpose, dim3(4096),   dim3(256), 0, stream, wq, wk, wv, wff, wqkvt, wfft);
    hipLaunchKernelGGL(k_ln,        dim3(2048),   dim3(256), 0, stream, x, g1, b1, h1);
    hipLaunchKernelGGL(k_gemm_qkv,  dim3(32, 24), dim3(256), 0, stream, h1, wqkvt, qb, kb, vtb);
    hipLaunchKernelGGL(k_attn,      dim3(32, 32), dim3(256), 0, stream, qb, kb, vtb, x, out1);
    hipLaunchKernelGGL(k_ln,        dim3(2048),   dim3(256), 0, stream, out1, g2, b2, h1);
    hipLaunchKernelGGL(k_gemm_ff,   dim3(32, 8),  dim3(256), 0, stream, h1, wfft, bff, out1, (float*)d_out);
}